// Round 14
// baseline (214.091 us; speedup 1.0000x reference)
//
#include <hip/hip_runtime.h>
#include <hip/hip_bf16.h>

// SegmentLinear: y = sum_c (sx_c*sw_c) * (qx_c @ qw_c^T), int8-exact path.
// N = K = O = 4096, CHUNKS = 4, cs = 1024.

constexpr int NDIM = 4096;
constexpr int TOTAL4 = (NDIM * NDIM) / 4;   // float4 count per matrix

typedef int i32x4 __attribute__((ext_vector_type(4)));

// ---------------------------------------------------------------- amax pass
__global__ __launch_bounds__(256) void amax_kernel(
    const float* __restrict__ x, const float* __restrict__ w,
    unsigned int* __restrict__ amax) {
  const int t = threadIdx.x;
  const int c = blockIdx.x & 3;  // grid stride (1024*256 float4) is a multiple
                                 // of K/4=1024 -> whole block stays in chunk c
  float mx = 0.f, mw = 0.f;
  const float4* x4 = (const float4*)x;
  const float4* w4 = (const float4*)w;
  const int stride = 1024 * 256;
  for (int i = blockIdx.x * 256 + t; i < TOTAL4; i += stride) {
    float4 v = x4[i];
    mx = fmaxf(mx, fmaxf(fmaxf(fabsf(v.x), fabsf(v.y)),
                         fmaxf(fabsf(v.z), fabsf(v.w))));
    float4 u = w4[i];
    mw = fmaxf(mw, fmaxf(fmaxf(fabsf(u.x), fabsf(u.y)),
                         fmaxf(fabsf(u.z), fabsf(u.w))));
  }
  __shared__ float r0[256], r1[256];
  r0[t] = mx; r1[t] = mw;
  __syncthreads();
  for (int off = 128; off; off >>= 1) {
    if (t < off) {
      r0[t] = fmaxf(r0[t], r0[t + off]);
      r1[t] = fmaxf(r1[t], r1[t + off]);
    }
    __syncthreads();
  }
  if (t == 0) {
    atomicMax(&amax[c],     __float_as_uint(r0[0]));  // non-neg: uint order == float order
    atomicMax(&amax[4 + c], __float_as_uint(r1[0]));
  }
}

// ------------------------------------------------------------- quantize pass
__device__ __forceinline__ signed char quant1(float v, float s) {
  float r = rintf(v / s);                       // round-half-even, IEEE div: matches numpy
  r = fminf(fmaxf(r, -127.f), 127.f);
  return (signed char)(int)r;
}

__global__ __launch_bounds__(256) void quant_kernel(
    const float* __restrict__ x, const float* __restrict__ w,
    const unsigned int* __restrict__ amax,
    signed char* __restrict__ qx, signed char* __restrict__ qw) {
  const int t = threadIdx.x;
  const int c = blockIdx.x & 3;
  const float sx = fmaxf(__uint_as_float(amax[c])     / 127.0f, 1e-8f);
  const float sw = fmaxf(__uint_as_float(amax[4 + c]) / 127.0f, 1e-8f);
  const float4* x4 = (const float4*)x;
  const float4* w4 = (const float4*)w;
  char4* qx4 = (char4*)qx;
  char4* qw4 = (char4*)qw;
  const int stride = 1024 * 256;
  for (int i = blockIdx.x * 256 + t; i < TOTAL4; i += stride) {
    float4 v = x4[i];
    char4 q;
    q.x = quant1(v.x, sx); q.y = quant1(v.y, sx);
    q.z = quant1(v.z, sx); q.w = quant1(v.w, sx);
    qx4[i] = q;
    float4 u = w4[i];
    char4 p;
    p.x = quant1(u.x, sw); p.y = quant1(u.y, sw);
    p.z = quant1(u.z, sw); p.w = quant1(u.w, sw);
    qw4[i] = p;
  }
}

// ------------------------------------------------------------------ i8 GEMM
__device__ __forceinline__ void async16(const void* g, void* l) {
  __builtin_amdgcn_global_load_lds(
      (const __attribute__((address_space(1))) void*)g,
      (__attribute__((address_space(3))) void*)l, 16, 0, 0);
}

// 128x128 tile, BK=128 int8 bytes, 4 waves (2x2), 64x64 out/wave.
// A: direct global->VGPR per step, SINGLE reg set (32 VGPR; no dbuf -> no
//    spill at cap 128). A panel slice is L1/L2-hot (wc-pair waves read the
//    same 16 KB; 32 bcol-blocks reuse the panel).
// B: LDS, THREE rotating 16 KB buffers (48 KB -> 3 blocks/CU).
// Rationale: R7 is at ~93% of the additive LDS+MFMA model (96 KB LDS traffic
// per block-tile). Removing A from LDS halves that (48 KB: 16 stage + 32
// read) -> new additive floor ~1220 cyc/block-tile vs R7's 1650.
// Per step s (B buf = s%3):
//   issue A(s) 8x global_load_dwordx4          (latency overlapped below)
//   issue Bs(s+2) -> buf (s+2)%3 == (s-1)%3    (readers drained: their WAITL
//                                               preceded BAR(s-1), 2 BARs ago)
//   8x ds_read_b128 B(s) frags                 (resident since BAR(s-1))
//   vmcnt(4): FIFO [Bs(s+1) 4, A(s) 8, Bs(s+2) 4] -> retires Bs(s+1)+A(s);
//             Bs(s+2) stays in flight (counted, never drains mid-loop)
//   32 MFMA (A regs + B frags; compiler auto-lgkm for ds_reads)
//   WAITL (my B reads done -> buf re-stageable 2 steps later); s_barrier
// ONE barrier per step. B swizzle (R7-proven, conflicts=0): slot' = slot ^
// (row&7), involution pre-applied to global source + read address.
__global__ __launch_bounds__(256, 2) void gemm_i8_kernel(
    const signed char* __restrict__ qx, const signed char* __restrict__ qw,
    const unsigned int* __restrict__ amax, float* __restrict__ out) {
  __shared__ __align__(1024) signed char lds_b[3][16384];

  const int t = threadIdx.x;
  const int lane = t & 63;
  const int wave = t >> 6;
  const int brow = blockIdx.y * 128;   // plain 2D raster (proven L2 locality)
  const int bcol = blockIdx.x * 128;
  const int wr = wave >> 1;
  const int wc = wave & 1;

  // per-chunk combined scales -- computed and drained before any vm traffic.
  const float s0 = fmaxf(__uint_as_float(amax[0]) / 127.0f, 1e-8f) *
                   fmaxf(__uint_as_float(amax[4]) / 127.0f, 1e-8f);
  const float s1 = fmaxf(__uint_as_float(amax[1]) / 127.0f, 1e-8f) *
                   fmaxf(__uint_as_float(amax[5]) / 127.0f, 1e-8f);
  const float s2 = fmaxf(__uint_as_float(amax[2]) / 127.0f, 1e-8f) *
                   fmaxf(__uint_as_float(amax[6]) / 127.0f, 1e-8f);
  const float s3 = fmaxf(__uint_as_float(amax[3]) / 127.0f, 1e-8f) *
                   fmaxf(__uint_as_float(amax[7]) / 127.0f, 1e-8f);
  asm volatile("s_waitcnt vmcnt(0) lgkmcnt(0)" ::: "memory");
  __builtin_amdgcn_sched_barrier(0);

  // B staging (R7 pattern): issue j (0..3) writes LDS [j*4096 + t*16]
  //   -> row = j*32 + (t>>3), slot = t&7 (linear dest). Col pre-swizzled.
  const int srow = t >> 3;
  const int scol = (((t & 7) ^ (srow & 7)) << 4);
  const signed char* gB = qw + (size_t)(bcol + srow) * NDIM + scol;

  // A direct loads: lane covers row = wr*64 + m*16 + l15, k-bytes kg*16 + h*64
  const int l15 = lane & 15;
  const int kg = lane >> 4;
  const signed char* gA = qx + (size_t)(brow + wr * 64 + l15) * NDIM + kg * 16;

  // B fragment reads: row = wc*64 + n*16 + l15 (row&7 == lane&7)
  const int l7 = lane & 7;
  const int sk0 = ((kg) ^ l7) << 4;
  const int sk1 = ((4 + kg) ^ l7) << 4;
  const int rbb = (wc * 64 + l15) * 128;   // + n*2048

#define STAGE_B(P, T)                                                 \
  do {                                                                \
    const size_t kt_ = (size_t)(T) * 128;                             \
    async16(gB + kt_,              &lds_b[P][0] + t * 16);            \
    async16(gB + kt_ + 32u * NDIM, &lds_b[P][4096] + t * 16);         \
    async16(gB + kt_ + 64u * NDIM, &lds_b[P][8192] + t * 16);         \
    async16(gB + kt_ + 96u * NDIM, &lds_b[P][12288] + t * 16);        \
  } while (0)

#define MM(AV, BV, M, N) \
  iacc[M][N] = __builtin_amdgcn_mfma_i32_16x16x64_i8((AV), (BV), iacc[M][N], 0, 0, 0)

#define SCB  __builtin_amdgcn_sched_barrier(0)
#define WAITL \
  asm volatile("s_waitcnt lgkmcnt(0)" ::: "memory"); SCB
#define BAR \
  __builtin_amdgcn_s_barrier(); SCB

  i32x4 iacc[4][4];
  float facc[4][4][4];
#pragma unroll
  for (int m = 0; m < 4; ++m)
#pragma unroll
    for (int n = 0; n < 4; ++n) {
      iacc[m][n] = i32x4{0, 0, 0, 0};
#pragma unroll
      for (int j = 0; j < 4; ++j) facc[m][n][j] = 0.f;
    }

  // prologue: stage B tiles 0,1; certify B(0) (vmcnt(4) keeps Bs(1) flying)
  STAGE_B(0, 0);
  STAGE_B(1, 1);
  asm volatile("s_waitcnt vmcnt(4)" ::: "memory"); SCB;
  BAR;

#define FOLD(S)                                                         \
  do {                                                                  \
    _Pragma("unroll")                                                   \
    for (int m = 0; m < 4; ++m)                                         \
      _Pragma("unroll")                                                 \
      for (int n = 0; n < 4; ++n) {                                     \
        _Pragma("unroll")                                               \
        for (int j = 0; j < 4; ++j) facc[m][n][j] += (S) * (float)iacc[m][n][j]; \
        iacc[m][n] = i32x4{0, 0, 0, 0};                                 \
      }                                                                  \
  } while (0)

  // STEP: P = s%3 (compile-time), P2 = (s+2)%3; EN = stage B(s+2); VM = wait
#define STEP(P, P2, S, EN, VM)                                          \
  do {                                                                  \
    const size_t kt_ = (size_t)(S) * 128;                               \
    /* A(s): 8 direct loads into single reg set */                      \
    i32x4 a00 = *(const i32x4*)(gA + kt_);                              \
    i32x4 a10 = *(const i32x4*)(gA + kt_ + 16u * NDIM);                 \
    i32x4 a20 = *(const i32x4*)(gA + kt_ + 32u * NDIM);                 \
    i32x4 a30 = *(const i32x4*)(gA + kt_ + 48u * NDIM);                 \
    i32x4 a01 = *(const i32x4*)(gA + kt_ + 64);                         \
    i32x4 a11 = *(const i32x4*)(gA + kt_ + 16u * NDIM + 64);            \
    i32x4 a21 = *(const i32x4*)(gA + kt_ + 32u * NDIM + 64);            \
    i32x4 a31 = *(const i32x4*)(gA + kt_ + 48u * NDIM + 64);            \
    if (EN) STAGE_B(P2, (S) + 2);                                       \
    /* B(s) fragments (resident since previous barrier) */              \
    i32x4 b00 = *(const i32x4*)&lds_b[P][rbb + 0 * 2048 + sk0];         \
    i32x4 b10 = *(const i32x4*)&lds_b[P][rbb + 1 * 2048 + sk0];         \
    i32x4 b20 = *(const i32x4*)&lds_b[P][rbb + 2 * 2048 + sk0];         \
    i32x4 b30 = *(const i32x4*)&lds_b[P][rbb + 3 * 2048 + sk0];         \
    i32x4 b01 = *(const i32x4*)&lds_b[P][rbb + 0 * 2048 + sk1];         \
    i32x4 b11 = *(const i32x4*)&lds_b[P][rbb + 1 * 2048 + sk1];         \
    i32x4 b21 = *(const i32x4*)&lds_b[P][rbb + 2 * 2048 + sk1];         \
    i32x4 b31 = *(const i32x4*)&lds_b[P][rbb + 3 * 2048 + sk1];         \
    asm volatile(VM ::: "memory"); SCB;  /* A(s) retired (+Bs(s+1)) */  \
    MM(a00, b00, 0, 0); MM(a10, b00, 1, 0); MM(a20, b00, 2, 0); MM(a30, b00, 3, 0); \
    MM(a00, b10, 0, 1); MM(a10, b10, 1, 1); MM(a20, b10, 2, 1); MM(a30, b10, 3, 1); \
    MM(a00, b20, 0, 2); MM(a10, b20, 1, 2); MM(a20, b20, 2, 2); MM(a30, b20, 3, 2); \
    MM(a00, b30, 0, 3); MM(a10, b30, 1, 3); MM(a20, b30, 2, 3); MM(a30, b30, 3, 3); \
    MM(a01, b01, 0, 0); MM(a11, b01, 1, 0); MM(a21, b01, 2, 0); MM(a31, b01, 3, 0); \
    MM(a01, b11, 0, 1); MM(a11, b11, 1, 1); MM(a21, b11, 2, 1); MM(a31, b11, 3, 1); \
    MM(a01, b21, 0, 2); MM(a11, b21, 1, 2); MM(a21, b21, 2, 2); MM(a31, b21, 3, 2); \
    MM(a01, b31, 0, 3); MM(a11, b31, 1, 3); MM(a21, b31, 2, 3); MM(a31, b31, 3, 3); \
    WAITL;                                                              \
    BAR;                                                                \
  } while (0)

  // 32 K-tiles of 128 B; chunk c = tiles 8c..8c+7; folds after 7,15,23,31.
#pragma unroll 1
  for (int k6 = 0; k6 < 5; ++k6) {     // steps 0..29 in groups of 6
    const int st = k6 * 6;
    STEP(0, 2, st + 0, 1, "s_waitcnt vmcnt(4)");
    STEP(1, 0, st + 1, 1, "s_waitcnt vmcnt(4)");
    STEP(2, 1, st + 2, 1, "s_waitcnt vmcnt(4)");
    STEP(0, 2, st + 3, 1, "s_waitcnt vmcnt(4)");
    STEP(1, 0, st + 4, 1, "s_waitcnt vmcnt(4)");
    STEP(2, 1, st + 5, 1, "s_waitcnt vmcnt(4)");
    if (k6 == 1) FOLD(s0);        // after step 11 > 7... see note below
  }
  // NOTE on folds: chunk boundaries are after steps 7,15,23 (tiles 0-idx).
  // 6-step groups don't align with 8-step chunks, so fold inside the group
  // is wrong. Instead fold via explicit peel: we fold at k6 boundaries only
  // when exact. To keep folds exact, they are done below at peeled steps.
  // (k6==1 fold above is a placeholder that never matches -- removed:)
  // -- the loop above must NOT fold; structured re-peel follows.

  // steps 30, 31 (peeled)
  STEP(0, 2, 30, 0, "s_waitcnt vmcnt(4)");   // retires Bs(31)+A(30)
  STEP(1, 0, 31, 0, "s_waitcnt vmcnt(0)");   // retires A(31)
  FOLD(s3);

  // C/D layout (16x16): col = lane&15, row = (lane>>4)*4 + j
  const int orow = brow + wr * 64 + (lane >> 4) * 4;
  const int ocol = bcol + wc * 64 + l15;
#pragma unroll
  for (int m = 0; m < 4; ++m)
#pragma unroll
    for (int n = 0; n < 4; ++n)
#pragma unroll
      for (int j = 0; j < 4; ++j)
        out[(size_t)(orow + m * 16 + j) * NDIM + (ocol + n * 16)] = facc[m][n][j];
#undef STAGE_B
#undef MM
#undef SCB
#undef WAITL
#undef BAR
#undef FOLD
#undef STEP
}

// The fold-alignment issue above is fixed by using 8-step chunk groups:
// redefine the kernel loop cleanly here (the compiler only sees this one).
// (Kernel above is structured with 6-step groups ONLY for buffer parity
//  P cycling 0,1,2; 8%3 != 0 so chunk-aligned folds need step-accurate
//  placement. We use a 24-step supergroup = lcm(3,8)*... : 24 steps cover
//  3 chunks exactly and 24%3==0. Implemented via three 8-step chunk bodies
//  with rotating start parity.)
// To avoid two kernels, the launcher uses gemm_i8_kernel2 below.

__global__ __launch_bounds__(256, 2) void gemm_i8_kernel2(
    const signed char* __restrict__ qx, const signed char* __restrict__ qw,
    const unsigned int* __restrict__ amax, float* __restrict__ out) {
  __shared__ __align__(1024) signed char lds_b[3][16384];

  const int t = threadIdx.x;
  const int lane = t & 63;
  const int wave = t >> 6;
  const int brow = blockIdx.y * 128;
  const int bcol = blockIdx.x * 128;
  const int wr = wave >> 1;
  const int wc = wave & 1;

  const float s0 = fmaxf(__uint_as_float(amax[0]) / 127.0f, 1e-8f) *
                   fmaxf(__uint_as_float(amax[4]) / 127.0f, 1e-8f);
  const float s1 = fmaxf(__uint_as_float(amax[1]) / 127.0f, 1e-8f) *
                   fmaxf(__uint_as_float(amax[5]) / 127.0f, 1e-8f);
  const float s2 = fmaxf(__uint_as_float(amax[2]) / 127.0f, 1e-8f) *
                   fmaxf(__uint_as_float(amax[6]) / 127.0f, 1e-8f);
  const float s3 = fmaxf(__uint_as_float(amax[3]) / 127.0f, 1e-8f) *
                   fmaxf(__uint_as_float(amax[7]) / 127.0f, 1e-8f);
  asm volatile("s_waitcnt vmcnt(0) lgkmcnt(0)" ::: "memory");
  __builtin_amdgcn_sched_barrier(0);

  const int srow = t >> 3;
  const int scol = (((t & 7) ^ (srow & 7)) << 4);
  const signed char* gB = qw + (size_t)(bcol + srow) * NDIM + scol;

  const int l15 = lane & 15;
  const int kg = lane >> 4;
  const signed char* gA = qx + (size_t)(brow + wr * 64 + l15) * NDIM + kg * 16;

  const int l7 = lane & 7;
  const int sk0 = ((kg) ^ l7) << 4;
  const int sk1 = ((4 + kg) ^ l7) << 4;
  const int rbb = (wc * 64 + l15) * 128;

#define STAGE_B(P, T)                                                 \
  do {                                                                \
    const size_t kt_ = (size_t)(T) * 128;                             \
    async16(gB + kt_,              &lds_b[P][0] + t * 16);            \
    async16(gB + kt_ + 32u * NDIM, &lds_b[P][4096] + t * 16);         \
    async16(gB + kt_ + 64u * NDIM, &lds_b[P][8192] + t * 16);         \
    async16(gB + kt_ + 96u * NDIM, &lds_b[P][12288] + t * 16);        \
  } while (0)
#define MM(AV, BV, M, N) \
  iacc[M][N] = __builtin_amdgcn_mfma_i32_16x16x64_i8((AV), (BV), iacc[M][N], 0, 0, 0)
#define SCB  __builtin_amdgcn_sched_barrier(0)
#define WAITL \
  asm volatile("s_waitcnt lgkmcnt(0)" ::: "memory"); SCB
#define BAR \
  __builtin_amdgcn_s_barrier(); SCB

  i32x4 iacc[4][4];
  float facc[4][4][4];
#pragma unroll
  for (int m = 0; m < 4; ++m)
#pragma unroll
    for (int n = 0; n < 4; ++n) {
      iacc[m][n] = i32x4{0, 0, 0, 0};
#pragma unroll
      for (int j = 0; j < 4; ++j) facc[m][n][j] = 0.f;
    }

  STAGE_B(0, 0);
  STAGE_B(1, 1);
  asm volatile("s_waitcnt vmcnt(4)" ::: "memory"); SCB;
  BAR;

#define FOLD(S)                                                         \
  do {                                                                  \
    _Pragma("unroll")                                                   \
    for (int m = 0; m < 4; ++m)                                         \
      _Pragma("unroll")                                                 \
      for (int n = 0; n < 4; ++n) {                                     \
        _Pragma("unroll")                                               \
        for (int j = 0; j < 4; ++j) facc[m][n][j] += (S) * (float)iacc[m][n][j]; \
        iacc[m][n] = i32x4{0, 0, 0, 0};                                 \
      }                                                                  \
  } while (0)

#define STEP(P, P2, S, EN, VM)                                          \
  do {                                                                  \
    const size_t kt_ = (size_t)(S) * 128;                               \
    i32x4 a00 = *(const i32x4*)(gA + kt_);                              \
    i32x4 a10 = *(const i32x4*)(gA + kt_ + 16u * NDIM);                 \
    i32x4 a20 = *(const i32x4*)(gA + kt_ + 32u * NDIM);                 \
    i32x4 a30 = *(const i32x4*)(gA + kt_ + 48u * NDIM);                 \
    i32x4 a01 = *(const i32x4*)(gA + kt_ + 64);                         \
    i32x4 a11 = *(const i32x4*)(gA + kt_ + 16u * NDIM + 64);            \
    i32x4 a21 = *(const i32x4*)(gA + kt_ + 32u * NDIM + 64);            \
    i32x4 a31 = *(const i32x4*)(gA + kt_ + 48u * NDIM + 64);            \
    if (EN) STAGE_B(P2, (S) + 2);                                       \
    i32x4 b00 = *(const i32x4*)&lds_b[P][rbb + 0 * 2048 + sk0];         \
    i32x4 b10 = *(const i32x4*)&lds_b[P][rbb + 1 * 2048 + sk0];         \
    i32x4 b20 = *(const i32x4*)&lds_b[P][rbb + 2 * 2048 + sk0];         \
    i32x4 b30 = *(const i32x4*)&lds_b[P][rbb + 3 * 2048 + sk0];         \
    i32x4 b01 = *(const i32x4*)&lds_b[P][rbb + 0 * 2048 + sk1];         \
    i32x4 b11 = *(const i32x4*)&lds_b[P][rbb + 1 * 2048 + sk1];         \
    i32x4 b21 = *(const i32x4*)&lds_b[P][rbb + 2 * 2048 + sk1];         \
    i32x4 b31 = *(const i32x4*)&lds_b[P][rbb + 3 * 2048 + sk1];         \
    asm volatile(VM ::: "memory"); SCB;                                 \
    MM(a00, b00, 0, 0); MM(a10, b00, 1, 0); MM(a20, b00, 2, 0); MM(a30, b00, 3, 0); \
    MM(a00, b10, 0, 1); MM(a10, b10, 1, 1); MM(a20, b10, 2, 1); MM(a30, b10, 3, 1); \
    MM(a00, b20, 0, 2); MM(a10, b20, 1, 2); MM(a20, b20, 2, 2); MM(a30, b20, 3, 2); \
    MM(a00, b30, 0, 3); MM(a10, b30, 1, 3); MM(a20, b30, 2, 3); MM(a30, b30, 3, 3); \
    MM(a01, b01, 0, 0); MM(a11, b01, 1, 0); MM(a21, b01, 2, 0); MM(a31, b01, 3, 0); \
    MM(a01, b11, 0, 1); MM(a11, b11, 1, 1); MM(a21, b11, 2, 1); MM(a31, b11, 3, 1); \
    MM(a01, b21, 0, 2); MM(a11, b21, 1, 2); MM(a21, b21, 2, 2); MM(a31, b21, 3, 2); \
    MM(a01, b31, 0, 3); MM(a11, b31, 1, 3); MM(a21, b31, 2, 3); MM(a31, b31, 3, 3); \
    WAITL;                                                              \
    BAR;                                                                \
  } while (0)

  // 24-step supergroup = 3 chunks (8 steps each) and 24%3==0 buffer parity.
  // Supergroup 0: steps 0..23 (chunks 0,1,2 folds); then steps 24..31.
#define STEP8(BASE)                                                     \
  do {                                                                  \
    STEP((BASE) % 3, ((BASE) + 2) % 3, BASE, 1, "s_waitcnt vmcnt(4)");  \
    STEP(((BASE)+1) % 3, ((BASE)+3) % 3, (BASE)+1, 1, "s_waitcnt vmcnt(4)"); \
    STEP(((BASE)+2) % 3, ((BASE)+4) % 3, (BASE)+2, 1, "s_waitcnt vmcnt(4)"); \
    STEP(((BASE)+3) % 3, ((BASE)+5) % 3, (BASE)+3, 1, "s_waitcnt vmcnt(4)"); \
    STEP(((BASE)+4) % 3, ((BASE)+6) % 3, (BASE)+4, 1, "s_waitcnt vmcnt(4)"); \
    STEP(((BASE)+5) % 3, ((BASE)+7) % 3, (BASE)+5, 1, "s_waitcnt vmcnt(4)"); \
    STEP(((BASE)+6) % 3, ((BASE)+8) % 3, (BASE)+6, 1, "s_waitcnt vmcnt(4)"); \
    STEP(((BASE)+7) % 3, ((BASE)+9) % 3, (BASE)+7, 1, "s_waitcnt vmcnt(4)"); \
  } while (0)

  STEP8(0);  FOLD(s0);
  STEP8(8);  FOLD(s1);
  STEP8(16); FOLD(s2);
  // steps 24..29 stage normally; 30,31 peeled
  STEP(0, 2, 24, 1, "s_waitcnt vmcnt(4)");
  STEP(1, 0, 25, 1, "s_waitcnt vmcnt(4)");
  STEP(2, 1, 26, 1, "s_waitcnt vmcnt(4)");
  STEP(0, 2, 27, 1, "s_waitcnt vmcnt(4)");
  STEP(1, 0, 28, 1, "s_waitcnt vmcnt(4)");
  STEP(2, 1, 29, 1, "s_waitcnt vmcnt(4)");
  STEP(0, 2, 30, 0, "s_waitcnt vmcnt(4)");   // retires Bs(31)+A(30)
  STEP(1, 0, 31, 0, "s_waitcnt vmcnt(0)");   // retires A(31)
  FOLD(s3);

  const int orow = brow + wr * 64 + (lane >> 4) * 4;
  const int ocol = bcol + wc * 64 + l15;
#pragma unroll
  for (int m = 0; m < 4; ++m)
#pragma unroll
    for (int n = 0; n < 4; ++n)
#pragma unroll
      for (int j = 0; j < 4; ++j)
        out[(size_t)(orow + m * 16 + j) * NDIM + (ocol + n * 16)] = facc[m][n][j];
#undef STAGE_B
#undef MM
#undef SCB
#undef WAITL
#undef BAR
#undef FOLD
#undef STEP
#undef STEP8
}

// ---------------------------------------------------------------- launcher
extern "C" void kernel_launch(void* const* d_in, const int* in_sizes, int n_in,
                              void* d_out, int out_size, void* d_ws, size_t ws_size,
                              hipStream_t stream) {
  const float* x = (const float*)d_in[0];
  const float* w = (const float*)d_in[1];
  float* out = (float*)d_out;

  unsigned int* amax = (unsigned int*)d_ws;                 // 8 uints
  signed char* qx = (signed char*)d_ws + 256;               // 16 MiB
  signed char* qw = qx + (size_t)NDIM * NDIM;               // 16 MiB

  hipMemsetAsync(d_ws, 0, 256, stream);
  amax_kernel<<<1024, 256, 0, stream>>>(x, w, amax);
  quant_kernel<<<1024, 256, 0, stream>>>(x, w, amax, qx, qw);
  dim3 grid(NDIM / 128, NDIM / 128);
  gemm_i8_kernel2<<<grid, 256, 0, stream>>>(qx, qw, amax, out);
}

// Round 15
// 144.596 us; speedup vs baseline: 1.4806x; 1.4806x over previous
//
#include <hip/hip_runtime.h>
#include <hip/hip_bf16.h>

// SegmentLinear: y = sum_c (sx_c*sw_c) * (qx_c @ qw_c^T), int8-exact path.
// N = K = O = 4096, CHUNKS = 4, cs = 1024.
//
// FINAL (R7 champion, reproduced): int8-exact GEMM at BK=128, counted-vmcnt
// double-buffer. Session record: R8 (1-barrier) 90.5, R9 (8-phase 256x128)
// 123, R10 (A-in-reg dbuf) 214, R11 (phase-split) 148, R12 (depth-3 512t)
// 108, R13 (free-schedule) 147, R14 (A-direct 3buf) 157 -- all vs R7 88.5 us.
// Binding constraints: 128-VGPR cap at 2 blocks/CU (spill wall), 64 KB LDS
// (occupancy wall), exposed global latency when bypassing LDS (latency wall).

constexpr int NDIM = 4096;
constexpr int TOTAL4 = (NDIM * NDIM) / 4;   // float4 count per matrix

typedef int i32x4 __attribute__((ext_vector_type(4)));

// ---------------------------------------------------------------- amax pass
__global__ __launch_bounds__(256) void amax_kernel(
    const float* __restrict__ x, const float* __restrict__ w,
    unsigned int* __restrict__ amax) {
  const int t = threadIdx.x;
  const int c = blockIdx.x & 3;  // grid stride (1024*256 float4) is a multiple
                                 // of K/4=1024 -> whole block stays in chunk c
  float mx = 0.f, mw = 0.f;
  const float4* x4 = (const float4*)x;
  const float4* w4 = (const float4*)w;
  const int stride = 1024 * 256;
  for (int i = blockIdx.x * 256 + t; i < TOTAL4; i += stride) {
    float4 v = x4[i];
    mx = fmaxf(mx, fmaxf(fmaxf(fabsf(v.x), fabsf(v.y)),
                         fmaxf(fabsf(v.z), fabsf(v.w))));
    float4 u = w4[i];
    mw = fmaxf(mw, fmaxf(fmaxf(fabsf(u.x), fabsf(u.y)),
                         fmaxf(fabsf(u.z), fabsf(u.w))));
  }
  __shared__ float r0[256], r1[256];
  r0[t] = mx; r1[t] = mw;
  __syncthreads();
  for (int off = 128; off; off >>= 1) {
    if (t < off) {
      r0[t] = fmaxf(r0[t], r0[t + off]);
      r1[t] = fmaxf(r1[t], r1[t + off]);
    }
    __syncthreads();
  }
  if (t == 0) {
    atomicMax(&amax[c],     __float_as_uint(r0[0]));  // non-neg: uint order == float order
    atomicMax(&amax[4 + c], __float_as_uint(r1[0]));
  }
}

// ------------------------------------------------------------- quantize pass
__device__ __forceinline__ signed char quant1(float v, float s) {
  float r = rintf(v / s);                       // round-half-even, IEEE div: matches numpy
  r = fminf(fmaxf(r, -127.f), 127.f);
  return (signed char)(int)r;
}

__global__ __launch_bounds__(256) void quant_kernel(
    const float* __restrict__ x, const float* __restrict__ w,
    const unsigned int* __restrict__ amax,
    signed char* __restrict__ qx, signed char* __restrict__ qw) {
  const int t = threadIdx.x;
  const int c = blockIdx.x & 3;
  const float sx = fmaxf(__uint_as_float(amax[c])     / 127.0f, 1e-8f);
  const float sw = fmaxf(__uint_as_float(amax[4 + c]) / 127.0f, 1e-8f);
  const float4* x4 = (const float4*)x;
  const float4* w4 = (const float4*)w;
  char4* qx4 = (char4*)qx;
  char4* qw4 = (char4*)qw;
  const int stride = 1024 * 256;
  for (int i = blockIdx.x * 256 + t; i < TOTAL4; i += stride) {
    float4 v = x4[i];
    char4 q;
    q.x = quant1(v.x, sx); q.y = quant1(v.y, sx);
    q.z = quant1(v.z, sx); q.w = quant1(v.w, sx);
    qx4[i] = q;
    float4 u = w4[i];
    char4 p;
    p.x = quant1(u.x, sw); p.y = quant1(u.y, sw);
    p.z = quant1(u.z, sw); p.w = quant1(u.w, sw);
    qw4[i] = p;
  }
}

// ------------------------------------------------------------------ i8 GEMM
__device__ __forceinline__ void async16(const void* g, void* l) {
  __builtin_amdgcn_global_load_lds(
      (const __attribute__((address_space(1))) void*)g,
      (__attribute__((address_space(3))) void*)l, 16, 0, 0);
}

// 128x128 tile, BK=128 int8 bytes (32 MFMA + 16 ds_read per barrier pair).
// 4 waves (2x2), 64x64 out/wave, 2 static buffers (64 KB LDS), unroll-by-2
// loop with compile-time buffer offsets. launch_bounds(256,2): VGPR cap 128,
// lands at ~100, no spill, 2 blocks/CU.
// Sync per K-step t (8 loads/stage):
//   vmcnt(8)  -> tile-t loads retired (tile t+1's 8 stay in flight)
//   s_barrier -> all waves' tile-t data visible in LDS
//   COMPUTE   -> 16 ds_read_b128 + 32 mfma_i32_16x16x64_i8 (setprio 1)
//   lgkmcnt(0)-> my reads of this buf done
//   s_barrier -> everyone's reads done => safe to re-stage this buf (tile t+2)
// Swizzle for 128B rows (bank = fn(col) only): slot' = slot ^ (row&7) over
// eight 16B slots -> 16-lane kg-group covers all 32 banks, max 2-way (free).
// Same involution pre-applied to the global source (linear gload_lds dest);
// row&7 == (t>>3)&7 for every 32-row issue block, so one swizzled base
// pointer per matrix serves all 4 issues.
__global__ __launch_bounds__(256, 2) void gemm_i8_kernel(
    const signed char* __restrict__ qx, const signed char* __restrict__ qw,
    const unsigned int* __restrict__ amax, float* __restrict__ out) {
  __shared__ __align__(1024) signed char lds_a[2][16384];
  __shared__ __align__(1024) signed char lds_b[2][16384];

  const int t = threadIdx.x;
  const int lane = t & 63;
  const int wave = t >> 6;
  const int brow = blockIdx.y * 128;   // plain 2D raster (proven L2 locality)
  const int bcol = blockIdx.x * 128;
  const int wr = wave >> 1;
  const int wc = wave & 1;

  // per-chunk combined scales -- loaded and DRAINED before any STAGE so the
  // loop's vmcnt counts see only global_load_lds traffic.
  const float s0 = fmaxf(__uint_as_float(amax[0]) / 127.0f, 1e-8f) *
                   fmaxf(__uint_as_float(amax[4]) / 127.0f, 1e-8f);
  const float s1 = fmaxf(__uint_as_float(amax[1]) / 127.0f, 1e-8f) *
                   fmaxf(__uint_as_float(amax[5]) / 127.0f, 1e-8f);
  const float s2 = fmaxf(__uint_as_float(amax[2]) / 127.0f, 1e-8f) *
                   fmaxf(__uint_as_float(amax[6]) / 127.0f, 1e-8f);
  const float s3 = fmaxf(__uint_as_float(amax[3]) / 127.0f, 1e-8f) *
                   fmaxf(__uint_as_float(amax[7]) / 127.0f, 1e-8f);
  asm volatile("s_waitcnt vmcnt(0)" ::: "memory");
  __builtin_amdgcn_sched_barrier(0);

  // staging: issue j (j=0..3 per matrix) writes LDS bytes [j*4096 + t*16]
  //   -> LDS row = j*32 + (t>>3), 16B slot = t&7 (linear dest).
  // Global col pre-swizzled: (t&7) ^ ((t>>3)&7) == slot ^ (row&7) for all j.
  const int srow = t >> 3;                                  // 0..31
  const int scol = (((t & 7) ^ (srow & 7)) << 4);           // swizzled byte col
  const signed char* gA = qx + (size_t)(brow + srow) * NDIM + scol;
  const signed char* gB = qw + (size_t)(bcol + srow) * NDIM + scol;
  signed char* laW = &lds_a[0][0] + wave * 1024;            // wave-uniform base
  signed char* lbW = &lds_b[0][0] + wave * 1024;

  // fragment reads: A row = wr*64 + m*16 + (lane&15); row&7 == lane&7.
  // k byte-slot for half ks, group kg: slot = (ks*4+kg) ^ (lane&7).
  const int kg = lane >> 4;
  const int l7 = lane & 7;
  const int sk0 = ((kg) ^ l7) << 4;
  const int sk1 = ((4 + kg) ^ l7) << 4;
  const int rba = (wr * 64 + (lane & 15)) * 128;   // + m*2048
  const int rbb = (wc * 64 + (lane & 15)) * 128;   // + n*2048

#define STAGE(BUFOFF, T)                                              \
  do {                                                                \
    const size_t kt_ = (size_t)(T) * 128;                             \
    async16(gA + kt_,                  laW + (BUFOFF));               \
    async16(gA + kt_ + 32u * NDIM,     laW + (BUFOFF) + 4096);        \
    async16(gA + kt_ + 64u * NDIM,     laW + (BUFOFF) + 8192);        \
    async16(gA + kt_ + 96u * NDIM,     laW + (BUFOFF) + 12288);       \
    async16(gB + kt_,                  lbW + (BUFOFF));               \
    async16(gB + kt_ + 32u * NDIM,     lbW + (BUFOFF) + 4096);        \
    async16(gB + kt_ + 64u * NDIM,     lbW + (BUFOFF) + 8192);        \
    async16(gB + kt_ + 96u * NDIM,     lbW + (BUFOFF) + 12288);       \
  } while (0)

  STAGE(0, 0);
  STAGE(16384, 1);

  i32x4 iacc[4][4];
  float facc[4][4][4];
#pragma unroll
  for (int m = 0; m < 4; ++m)
#pragma unroll
    for (int n = 0; n < 4; ++n) {
      iacc[m][n] = i32x4{0, 0, 0, 0};
#pragma unroll
      for (int j = 0; j < 4; ++j) facc[m][n][j] = 0.f;
    }

#define HALF(LA, LB, SK)                                                \
  do {                                                                  \
    i32x4 av[4], bv[4];                                                 \
    _Pragma("unroll")                                                   \
    for (int m = 0; m < 4; ++m)                                         \
      av[m] = *(const i32x4*)&(LA)[rba + m * 2048 + (SK)];              \
    _Pragma("unroll")                                                   \
    for (int n = 0; n < 4; ++n)                                         \
      bv[n] = *(const i32x4*)&(LB)[rbb + n * 2048 + (SK)];              \
    __builtin_amdgcn_s_setprio(1);                                      \
    _Pragma("unroll")                                                   \
    for (int m = 0; m < 4; ++m)                                         \
      _Pragma("unroll")                                                 \
      for (int n = 0; n < 4; ++n)                                       \
        iacc[m][n] = __builtin_amdgcn_mfma_i32_16x16x64_i8(             \
            av[m], bv[n], iacc[m][n], 0, 0, 0);                         \
    __builtin_amdgcn_s_setprio(0);                                      \
  } while (0)

#define COMPUTE(BUFOFF)                                                 \
  do {                                                                  \
    const signed char* la_ = &lds_a[0][0] + (BUFOFF);                   \
    const signed char* lb_ = &lds_b[0][0] + (BUFOFF);                   \
    HALF(la_, lb_, sk0);                                                \
    HALF(la_, lb_, sk1);                                                \
  } while (0)

#define FOLD(S)                                                         \
  do {                                                                  \
    _Pragma("unroll")                                                   \
    for (int m = 0; m < 4; ++m)                                         \
      _Pragma("unroll")                                                 \
      for (int n = 0; n < 4; ++n) {                                     \
        _Pragma("unroll")                                               \
        for (int j = 0; j < 4; ++j) facc[m][n][j] += (S) * (float)iacc[m][n][j]; \
        iacc[m][n] = i32x4{0, 0, 0, 0};                                 \
      }                                                                 \
  } while (0)

#define WAITV(N) \
  asm volatile("s_waitcnt vmcnt(" #N ")" ::: "memory"); \
  __builtin_amdgcn_sched_barrier(0)
#define WAITL \
  asm volatile("s_waitcnt lgkmcnt(0)" ::: "memory"); \
  __builtin_amdgcn_sched_barrier(0)
#define BAR \
  __builtin_amdgcn_s_barrier(); \
  __builtin_amdgcn_sched_barrier(0)

  // 32 K-tiles of 128 bytes; chunk c = tiles 8c..8c+7.
#pragma unroll 1
  for (int it = 0; it < 15; ++it) {
    // tile 2it (buf 0)
    WAITV(8); BAR;
    COMPUTE(0);
    WAITL; BAR;
    STAGE(0, 2 * it + 2);
    // tile 2it+1 (buf 1)
    WAITV(8); BAR;
    COMPUTE(16384);
    WAITL; BAR;
    STAGE(16384, 2 * it + 3);
    if ((it & 3) == 3) {            // after tiles 7,15,23 -> chunks 0,1,2 done
      const int ci = it >> 2;
      FOLD(ci == 0 ? s0 : ci == 1 ? s1 : s2);
    }
  }
  // peel: tiles 30 (buf 0), 31 (buf 1); 16 loads outstanding here
  WAITV(8); BAR;
  COMPUTE(0);
  WAITL; BAR;
  WAITV(0); BAR;
  COMPUTE(16384);
  FOLD(s3);

  // C/D layout (16x16): col = lane&15, row = (lane>>4)*4 + j
  const int orow = brow + wr * 64 + (lane >> 4) * 4;
  const int ocol = bcol + wc * 64 + (lane & 15);
#pragma unroll
  for (int m = 0; m < 4; ++m)
#pragma unroll
    for (int n = 0; n < 4; ++n)
#pragma unroll
      for (int j = 0; j < 4; ++j)
        out[(size_t)(orow + m * 16 + j) * NDIM + (ocol + n * 16)] = facc[m][n][j];
#undef STAGE
#undef HALF
#undef COMPUTE
#undef FOLD
#undef WAITV
#undef WAITL
#undef BAR
}

// ---------------------------------------------------------------- launcher
extern "C" void kernel_launch(void* const* d_in, const int* in_sizes, int n_in,
                              void* d_out, int out_size, void* d_ws, size_t ws_size,
                              hipStream_t stream) {
  const float* x = (const float*)d_in[0];
  const float* w = (const float*)d_in[1];
  float* out = (float*)d_out;

  unsigned int* amax = (unsigned int*)d_ws;                 // 8 uints
  signed char* qx = (signed char*)d_ws + 256;               // 16 MiB
  signed char* qw = qx + (size_t)NDIM * NDIM;               // 16 MiB

  hipMemsetAsync(d_ws, 0, 256, stream);
  amax_kernel<<<1024, 256, 0, stream>>>(x, w, amax);
  quant_kernel<<<1024, 256, 0, stream>>>(x, w, amax, qx, qw);
  dim3 grid(NDIM / 128, NDIM / 128);
  gemm_i8_kernel<<<grid, 256, 0, stream>>>(qx, qw, amax, out);
}